// Round 5
// baseline (2645.654 us; speedup 1.0000x reference)
//
#include <hip/hip_runtime.h>

#define BATCH 64
#define SEQ   2048
#define EIN   256
#define HID   256

typedef _Float16 f16;
typedef _Float16 f16x2 __attribute__((ext_vector_type(2)));
typedef _Float16 f16x8 __attribute__((ext_vector_type(8)));
typedef float    f32x4 __attribute__((ext_vector_type(4)));

__device__ __forceinline__ float dot2(f16x2 a, f16x2 b, float c) {
#if __has_builtin(__builtin_amdgcn_fdot2)
    return __builtin_amdgcn_fdot2(a, b, c, false);
#else
    return c + (float)a[0] * (float)b[0] + (float)a[1] * (float)b[1];
#endif
}

// ---------------- cast f32 -> f16, 8 elems/thread ----------------
__global__ __launch_bounds__(256) void cast_f32_f16(
    const float* __restrict__ s, f16* __restrict__ d, int n)
{
    int i = (blockIdx.x * 256 + threadIdx.x) * 8;
    if (i >= n) return;
    const float4* sp = reinterpret_cast<const float4*>(s + i);
    float4 a = sp[0], b = sp[1];
    f16x8 v = { (f16)a.x, (f16)a.y, (f16)a.z, (f16)a.w,
                (f16)b.x, (f16)b.y, (f16)b.z, (f16)b.w };
    *reinterpret_cast<f16x8*>(d + i) = v;
}

// ---------------- projection GEMM: C(M,256) = A(M,K) @ W(256,K)^T + bias ----
__global__ __launch_bounds__(256, 2) void gemm_proj(
    const f16* __restrict__ A, const f16* __restrict__ W,
    const float* __restrict__ bias, f16* __restrict__ C, int K)
{
    const int tid  = threadIdx.x;
    const int wave = tid >> 6, lane = tid & 63;
    const int g    = lane >> 4, lr = lane & 15;
    const int bm   = blockIdx.x * 128;
    const int bn   = blockIdx.y * 128;
    const int wm   = (wave >> 1) * 64, wn = (wave & 1) * 64;

    __shared__ __align__(16) f16 As[128][72];
    __shared__ __align__(16) f16 Bs[128][72];

    f32x4 acc[4][4] = {};

    for (int kt = 0; kt < K; kt += 64) {
        __syncthreads();
#pragma unroll
        for (int i = 0; i < 4; ++i) {
            int c = i * 256 + tid;
            int r = c >> 3, sg = c & 7;
            *reinterpret_cast<f16x8*>(&As[r][sg * 8]) =
                *reinterpret_cast<const f16x8*>(A + (size_t)(bm + r) * K + kt + sg * 8);
            *reinterpret_cast<f16x8*>(&Bs[r][sg * 8]) =
                *reinterpret_cast<const f16x8*>(W + (size_t)(bn + r) * K + kt + sg * 8);
        }
        __syncthreads();
#pragma unroll
        for (int kf = 0; kf < 2; ++kf) {
            f16x8 af[4], bf[4];
#pragma unroll
            for (int f = 0; f < 4; ++f) {
                af[f] = *reinterpret_cast<const f16x8*>(&As[wm + f * 16 + lr][kf * 32 + g * 8]);
                bf[f] = *reinterpret_cast<const f16x8*>(&Bs[wn + f * 16 + lr][kf * 32 + g * 8]);
            }
#pragma unroll
            for (int fm = 0; fm < 4; ++fm)
#pragma unroll
                for (int fn = 0; fn < 4; ++fn)
                    acc[fm][fn] = __builtin_amdgcn_mfma_f32_16x16x32_f16(
                        af[fm], bf[fn], acc[fm][fn], 0, 0, 0);
        }
    }

#pragma unroll
    for (int fn = 0; fn < 4; ++fn) {
        float bv = bias[bn + wn + fn * 16 + lr];
#pragma unroll
        for (int fm = 0; fm < 4; ++fm) {
#pragma unroll
            for (int i = 0; i < 4; ++i) {
                int row = bm + wm + fm * 16 + g * 4 + i;
                int col = bn + wn + fn * 16 + lr;
                C[(size_t)row * 256 + col] = (f16)(acc[fm][fn][i] + bv);
            }
        }
    }
}

// ---------------- recurrent scan: one WG per (batch, direction) -------------
// VALU dot-product path: thread t owns output unit t. Whh row t lives in 128
// f16x2 VGPRs; h (256 f16) broadcast-read from LDS each step via b128 chunks,
// software-pipelined 2 groups ahead (3 rotating register buffers A,B,C).
// 128 v_dot2_f32_f16 per step per thread (~256 cy/SIMD issue) replaces the
// 32-MFMA mapping (~621 cy/SIMD) -- zero duplicated work, no extraction tail.
template<bool WRITE_SEQ>
__global__ __launch_bounds__(256, 1) void rnn_scan(
    const f16* __restrict__ xpF, const f16* __restrict__ xpB,
    const float* __restrict__ WhhF, const float* __restrict__ bhhF,
    const float* __restrict__ WhhB, const float* __restrict__ bhhB,
    f16* __restrict__ seq_out,   // (B, SEQ, 512) f16 (used iff WRITE_SEQ)
    float* __restrict__ fin_out) // (B, 512) f32   (used iff !WRITE_SEQ)
{
    const int blk = blockIdx.x;
    const int b   = blk >> 1, dir = blk & 1;
    const f16*   xp  = dir ? xpB : xpF;
    const float* Whh = dir ? WhhB : WhhF;
    const float* bhh = dir ? bhhB : bhhF;

    const int tid = threadIdx.x;

    __shared__ __align__(16) f16 hbuf[2][256];

    // Pack this thread's Whh row (256 f32 -> 128 f16x2 VGPRs)
    f16x2 w[128];
    {
        const float4* wr4 = reinterpret_cast<const float4*>(Whh + (size_t)tid * 256);
#pragma unroll
        for (int q = 0; q < 64; ++q) {
            float4 v = wr4[q];
            w[2 * q]     = (f16x2){ (f16)v.x, (f16)v.y };
            w[2 * q + 1] = (f16x2){ (f16)v.z, (f16)v.w };
        }
    }
    const float bv = bhh[tid];

    hbuf[0][tid] = (f16)0.f;
    __syncthreads();

    // Walking pointers (over/under-run stays inside adjacent ws buffers;
    // those values are never consumed).
    const long long xstep = dir ? -256 : 256;
    const f16* xpre = xp + (long long)b * SEQ * 256
                         + (long long)(dir ? SEQ - 1 : 0) * 256 + tid;
    const long long sstep = dir ? -512 : 512;
    f16* sptr = nullptr;
    if (WRITE_SEQ)
        sptr = seq_out + ((long long)b * SEQ + (dir ? SEQ - 1 : 0)) * 512 + dir * 256 + tid;

    // 3-deep register prefetch ring for xproj
    f16 ring[4];
#pragma unroll
    for (int r = 0; r < 3; ++r) { ring[r] = *xpre; xpre += xstep; }

    float last_h = 0.f;

    for (int s4 = 0; s4 < SEQ; s4 += 4) {
#pragma unroll
        for (int u = 0; u < 4; ++u) {
            const f16x8* hb8 = reinterpret_cast<const f16x8*>(
                (u & 1) ? &hbuf[1][0] : &hbuf[0][0]);
            f16* nxt = (u & 1) ? &hbuf[0][0] : &hbuf[1][0];

            // rotating load buffers; issue 2 groups ahead of consumption
            f16x8 bA[8], bB[8], bC[8];
#pragma unroll
            for (int r = 0; r < 8; ++r) bA[r] = hb8[r];       // g0
#pragma unroll
            for (int r = 0; r < 8; ++r) bB[r] = hb8[8 + r];   // g1

            // prefetch xproj 3 steps ahead
            ring[(u + 3) & 3] = *xpre;
            xpre += xstep;

            float a0 = 0.f, a1 = 0.f, a2 = 0.f, a3 = 0.f;

            // ---- group 0 (bA), load g2 into bC
#pragma unroll
            for (int r = 0; r < 8; ++r) bC[r] = hb8[16 + r];
#pragma unroll
            for (int r = 0; r < 8; ++r) {
                const f16x2* pp = reinterpret_cast<const f16x2*>(&bA[r]);
                a0 = dot2(pp[0], w[r * 4 + 0], a0);
                a1 = dot2(pp[1], w[r * 4 + 1], a1);
                a2 = dot2(pp[2], w[r * 4 + 2], a2);
                a3 = dot2(pp[3], w[r * 4 + 3], a3);
            }
            // ---- group 1 (bB), load g3 into bA (freed)
#pragma unroll
            for (int r = 0; r < 8; ++r) bA[r] = hb8[24 + r];
#pragma unroll
            for (int r = 0; r < 8; ++r) {
                const f16x2* pp = reinterpret_cast<const f16x2*>(&bB[r]);
                a0 = dot2(pp[0], w[32 + r * 4 + 0], a0);
                a1 = dot2(pp[1], w[32 + r * 4 + 1], a1);
                a2 = dot2(pp[2], w[32 + r * 4 + 2], a2);
                a3 = dot2(pp[3], w[32 + r * 4 + 3], a3);
            }
            // ---- group 2 (bC)
#pragma unroll
            for (int r = 0; r < 8; ++r) {
                const f16x2* pp = reinterpret_cast<const f16x2*>(&bC[r]);
                a0 = dot2(pp[0], w[64 + r * 4 + 0], a0);
                a1 = dot2(pp[1], w[64 + r * 4 + 1], a1);
                a2 = dot2(pp[2], w[64 + r * 4 + 2], a2);
                a3 = dot2(pp[3], w[64 + r * 4 + 3], a3);
            }
            // ---- group 3 (bA)
#pragma unroll
            for (int r = 0; r < 8; ++r) {
                const f16x2* pp = reinterpret_cast<const f16x2*>(&bA[r]);
                a0 = dot2(pp[0], w[96 + r * 4 + 0], a0);
                a1 = dot2(pp[1], w[96 + r * 4 + 1], a1);
                a2 = dot2(pp[2], w[96 + r * 4 + 2], a2);
                a3 = dot2(pp[3], w[96 + r * 4 + 3], a3);
            }

            float mv  = (a0 + a1) + (a2 + a3);
            float pre = mv + (float)ring[u & 3] + bv;
            // tanh(x) = 1 - 2/(1 + 2^(x * 2/ln2))
            float e  = __builtin_exp2f(pre * 2.885390082f);
            float h  = 1.0f - 2.0f * __builtin_amdgcn_rcpf(e + 1.0f);
            f16 hh   = (f16)h;
            last_h   = h;

            nxt[tid] = hh;

            if (WRITE_SEQ) {
                *sptr = hh;
                sptr += sstep;
            }

            // write visible to all waves; no vmcnt drain (prefetch/stores fly)
            asm volatile("s_waitcnt lgkmcnt(0)" ::: "memory");
            __builtin_amdgcn_s_barrier();
            asm volatile("" ::: "memory");
        }
    }

    if (!WRITE_SEQ)
        fin_out[b * 512 + dir * 256 + tid] = last_h;
}

extern "C" void kernel_launch(void* const* d_in, const int* in_sizes, int n_in,
                              void* d_out, int out_size, void* d_ws, size_t ws_size,
                              hipStream_t stream)
{
    (void)in_sizes; (void)n_in; (void)out_size; (void)ws_size;

    const float* x      = (const float*)d_in[0];
    const float* Wih_f0 = (const float*)d_in[1];
    const float* bih_f0 = (const float*)d_in[2];
    const float* Whh_f0 = (const float*)d_in[3];
    const float* bhh_f0 = (const float*)d_in[4];
    const float* Wih_b0 = (const float*)d_in[5];
    const float* bih_b0 = (const float*)d_in[6];
    const float* Whh_b0 = (const float*)d_in[7];
    const float* bhh_b0 = (const float*)d_in[8];
    const float* Wih_f1 = (const float*)d_in[9];
    const float* bih_f1 = (const float*)d_in[10];
    const float* Whh_f1 = (const float*)d_in[11];
    const float* bhh_f1 = (const float*)d_in[12];
    const float* Wih_b1 = (const float*)d_in[13];
    const float* bih_b1 = (const float*)d_in[14];
    const float* Whh_b1 = (const float*)d_in[15];
    const float* bhh_b1 = (const float*)d_in[16];

    float* out = (float*)d_out;
    char*  ws  = (char*)d_ws;

    // ws layout (bytes)
    f16* xpF  = (f16*)(ws);                      // 67108864
    f16* xpB  = (f16*)(ws + 67108864);           // 67108864
    f16* out0 = (f16*)(ws + 134217728);          // 134217728
    f16* x16  = (f16*)(ws + 268435456);          // 67108864
    f16* wf0  = (f16*)(ws + 335544320);
    f16* wb0  = (f16*)(ws + 335544320 + 131072);
    f16* wf1  = (f16*)(ws + 335544320 + 262144);
    f16* wb1  = (f16*)(ws + 335544320 + 524288);

    // casts
    cast_f32_f16<<<16384, 256, 0, stream>>>(x, x16, 33554432);
    cast_f32_f16<<<32,    256, 0, stream>>>(Wih_f0, wf0, 65536);
    cast_f32_f16<<<32,    256, 0, stream>>>(Wih_b0, wb0, 65536);
    cast_f32_f16<<<64,    256, 0, stream>>>(Wih_f1, wf1, 131072);
    cast_f32_f16<<<64,    256, 0, stream>>>(Wih_b1, wb1, 131072);

    // layer 0 projections: K = 256
    gemm_proj<<<dim3(1024, 2), 256, 0, stream>>>(x16, wf0, bih_f0, xpF, 256);
    gemm_proj<<<dim3(1024, 2), 256, 0, stream>>>(x16, wb0, bih_b0, xpB, 256);

    // layer 0 scan -> out0 (B, SEQ, 512) f16
    rnn_scan<true><<<128, 256, 0, stream>>>(xpF, xpB, Whh_f0, bhh_f0, Whh_b0, bhh_b0,
                                            out0, nullptr);

    // layer 1 projections: K = 512
    gemm_proj<<<dim3(1024, 2), 256, 0, stream>>>(out0, wf1, bih_f1, xpF, 512);
    gemm_proj<<<dim3(1024, 2), 256, 0, stream>>>(out0, wb1, bih_b1, xpB, 512);

    // layer 1 scan -> final hiddens into d_out
    rnn_scan<false><<<128, 256, 0, stream>>>(xpF, xpB, Whh_f1, bhh_f1, Whh_b1, bhh_b1,
                                             nullptr, out);
}